// Round 13
// baseline (138.671 us; speedup 1.0000x reference)
//
#include <hip/hip_runtime.h>
#include <hip/hip_bf16.h>

#define NBATCH 256
#define NNODES 512
#define DIM    128
#define NTOT   (NBATCH*NNODES)   // 131072
#define NEDGE  (NTOT*8)          // 1048576
#define EPB    130816            // NNODES*(NNODES-1)/2
#define CAP    32

typedef __attribute__((ext_vector_type(8))) short  short8;
typedef __attribute__((ext_vector_type(4))) float  f32x4;

__device__ __forceinline__ unsigned short f2bf(float f){
  unsigned u = __builtin_bit_cast(unsigned, f);
  unsigned r = u + 0x7FFFu + ((u >> 16) & 1u);   // RNE
  return (unsigned short)(r >> 16);
}

// ---- fused prep: embW1 GEMM (bf16 out) + weight frag-swizzle + cnt zero ----
__global__ __launch_bounds__(256) void k_prep(
    const float* __restrict__ emb, const float* __restrict__ W1,
    unsigned short* __restrict__ embW1,
    const float* __restrict__ W2, const float* __restrict__ P1,
    const float* __restrict__ P2, unsigned short* __restrict__ wswz,
    int* __restrict__ cnt)
{
  const int tid = threadIdx.x;
  const int blk = blockIdx.x;
  __shared__ float er[2][DIM];
  if (blk < 256) {
    const int half = tid >> 7, c = tid & 127;
    const int r = blk*2 + half;
    er[half][c] = emb[r*DIM + c];
    __syncthreads();
    float acc = 0.f;
    #pragma unroll 8
    for (int k = 0; k < DIM; ++k) acc = fmaf(er[half][k], W1[k*DIM + c], acc);
    embW1[r*DIM + c] = f2bf(acc);
  } else if (blk < 448) {
    int idx = (blk - 256)*256 + tid;               // 49152 total
    int s = idx >> 14, rem = idx & 16383;
    int ks = rem >> 12, n = (rem >> 9) & 7, lane = (rem >> 3) & 63, j = rem & 7;
    int lg = lane >> 4, l15 = lane & 15;
    int k = ks*32 + lg*8 + j, c = n*16 + l15;
    const float* src = (s == 0) ? W2 : ((s == 1) ? P1 : P2);
    wswz[idx] = f2bf(src[k*DIM + c]);
  } else {
    cnt[(blk - 448)*256 + tid] = 0;                // 512 blocks -> 131072
  }
}

// ------- edge scatter, dst-range partitioned (XCD-local atomics/stores) ----
__global__ __launch_bounds__(256) void k_edges(const int* __restrict__ ei,
                                               const int* __restrict__ nf,
                                               int* __restrict__ cnt,
                                               unsigned short* __restrict__ slots){
  const int base = (blockIdx.x >> 3)*4096 + threadIdx.x;
  const int r    = blockIdx.x & 7;
  #pragma unroll
  for (int it = 0; it < 16; ++it) {
    const int e = base + it*256;
    const int d = ei[NEDGE + e];
    if ((d >> 14) == r) {
      const int s = ei[e];
      const int v = nf[s];
      const int pos = atomicAdd(&cnt[d], 1);
      if (pos < CAP) slots[(size_t)d*CAP + pos] = (unsigned short)v;
    }
  }
}

// ---- mega kernel: one block per batch, 1024 threads (16 waves/CU).
__global__ __launch_bounds__(1024, 4) void k_mega(
    const unsigned short* __restrict__ embW1, const int* __restrict__ nf,
    const int* __restrict__ cnt, const unsigned short* __restrict__ slots,
    const float* __restrict__ b1, const float* __restrict__ g1,
    const float* __restrict__ be1,
    const unsigned short* __restrict__ wswz,   // [3][4ks][8n][64lane][8j]
    const float* __restrict__ b2,  const float* __restrict__ pb1, const float* __restrict__ pb2,
    const float* __restrict__ ng,  const float* __restrict__ nbv,
    const float* __restrict__ eW1, const float* __restrict__ eb1,
    const float* __restrict__ eg,  const float* __restrict__ ebe,
    const float* __restrict__ eW2, const float* __restrict__ eb2,
    float* __restrict__ out)
{
  __shared__ unsigned short X[512][136];   // 139264 B
  __shared__ float gpart[16][128];
  __shared__ float mrow[128];
  __shared__ int   tq;
  const int tid   = threadIdx.x;
  const int bb    = blockIdx.x;            // batch index
  const int nbase = bb * NNODES;
  if (tid == 0) tq = 0;

  // ---------------- gather phase: 8 passes x 64 nodes ----------------
  {
    const int part = tid & 15;
    const short8* base8 = (const short8*)embW1;
    #pragma unroll 1
    for (int pass = 0; pass < 8; ++pass) {
      const int lnode = pass*64 + (tid >> 4);
      const int node  = nbase + lnode;
      const int self = nf[node];
      int m = cnt[node]; if (m > CAP) m = CAP;
      const unsigned short* sl = slots + (size_t)node*CAP;
      const uint4 sv0 = *(const uint4*)(sl);
      const uint4 sv1 = *(const uint4*)(sl + 8);
      const uint4 sv2 = *(const uint4*)(sl + 16);
      unsigned sw[12] = {sv0.x,sv0.y,sv0.z,sv0.w, sv1.x,sv1.y,sv1.z,sv1.w,
                         sv2.x,sv2.y,sv2.z,sv2.w};
      float a[8];
      {
        const float4* bp = (const float4*)(b1 + part*8);
        float4 x = bp[0], y = bp[1];
        a[0]=x.x; a[1]=x.y; a[2]=x.z; a[3]=x.w;
        a[4]=y.x; a[5]=y.y; a[6]=y.z; a[7]=y.w;
      }
#define ACC8(V) { _Pragma("unroll") \
      for (int i_ = 0; i_ < 8; ++i_) { \
        unsigned uu = ((unsigned)(unsigned short)(V)[i_]) << 16; \
        a[i_] += __builtin_bit_cast(float, uu); } }
      {
        short8 t0 = base8[(size_t)self*16 + part];
        short8 t[8];
        #pragma unroll
        for (int e = 0; e < 8; ++e) {
          unsigned id = (sw[e >> 1] >> ((e & 1)*16)) & 0xffffu;
          int idx = (e < m) ? (int)id : self;
          t[e] = base8[(size_t)idx*16 + part];
        }
        ACC8(t0)
        #pragma unroll
        for (int e = 0; e < 8; ++e) if (e < m) ACC8(t[e])
      }
      if (m > 8) {
        short8 t[8];
        #pragma unroll
        for (int e = 0; e < 8; ++e) {
          unsigned id = (sw[4 + (e >> 1)] >> ((e & 1)*16)) & 0xffffu;
          int idx = (e + 8 < m) ? (int)id : self;
          t[e] = base8[(size_t)idx*16 + part];
        }
        #pragma unroll
        for (int e = 0; e < 8; ++e) if (e + 8 < m) ACC8(t[e])
      }
      if (m > 16) {
        short8 t[8];
        #pragma unroll
        for (int e = 0; e < 8; ++e) {
          unsigned id = (sw[8 + (e >> 1)] >> ((e & 1)*16)) & 0xffffu;
          int idx = (e + 16 < m) ? (int)id : self;
          t[e] = base8[(size_t)idx*16 + part];
        }
        #pragma unroll
        for (int e = 0; e < 8; ++e) if (e + 16 < m) ACC8(t[e])
      }
      for (int e = 24; e < m; ++e) {
        short8 t = base8[(size_t)sl[e]*16 + part];
        ACC8(t)
      }
      float s = 0.f, qs = 0.f;
      #pragma unroll
      for (int i = 0; i < 8; ++i) { s += a[i]; qs += a[i]*a[i]; }
      #pragma unroll
      for (int msk = 1; msk < 16; msk <<= 1) {
        s  += __shfl_xor(s,  msk, 64);
        qs += __shfl_xor(qs, msk, 64);
      }
      const float mean = s * (1.f/128.f);
      const float var  = qs * (1.f/128.f) - mean*mean;
      const float rs   = rsqrtf(var + 1e-5f);
      const float4* gp = (const float4*)(g1  + part*8);
      const float4* ep = (const float4*)(be1 + part*8);
      float4 g0 = gp[0], g1v = gp[1], e0 = ep[0], e1v = ep[1];
      float gg[8] = {g0.x,g0.y,g0.z,g0.w, g1v.x,g1v.y,g1v.z,g1v.w};
      float eb[8] = {e0.x,e0.y,e0.z,e0.w, e1v.x,e1v.y,e1v.z,e1v.w};
      float v[8];
      #pragma unroll
      for (int i = 0; i < 8; ++i)
        v[i] = fmaxf((a[i] - mean)*rs*gg[i] + eb[i], 0.f);
      uint4 pk;
      pk.x = (unsigned)f2bf(v[0]) | ((unsigned)f2bf(v[1]) << 16);
      pk.y = (unsigned)f2bf(v[2]) | ((unsigned)f2bf(v[3]) << 16);
      pk.z = (unsigned)f2bf(v[4]) | ((unsigned)f2bf(v[5]) << 16);
      pk.w = (unsigned)f2bf(v[6]) | ((unsigned)f2bf(v[7]) << 16);
      *(uint4*)&X[lnode][part*8] = pk;
    }
  }
  __syncthreads();

  // ---- MLP phase: 16 waves, SWAPPED mfma(W,X) -> lane holds 4 consecutive
  //      cols of ONE row; X write-back becomes packed 8B uint2 writes. ----
  const int wave = tid >> 6, lane = tid & 63;
  const int l15 = lane & 15, lg = lane >> 4;
  const short8* ws8 = (const short8*)wswz;
  const float PRESCL = 0.29730177875068026f;   // 128^-0.25
  const int xrow0 = wave*16 + l15;             // p2*256 + xrow0
  const int cbase = lg*4;                      // col = n*16 + cbase + q

  #pragma unroll
  for (int s = 0; s < 3; ++s) {
    f32x4 acc[2][8];
    #pragma unroll
    for (int p2 = 0; p2 < 2; ++p2)
      #pragma unroll
      for (int n = 0; n < 8; ++n) acc[p2][n] = (f32x4){0.f,0.f,0.f,0.f};
    #pragma unroll
    for (int ks = 0; ks < 4; ++ks) {
      short8 bf[8];
      #pragma unroll
      for (int n = 0; n < 8; ++n) bf[n] = ws8[s*2048 + ks*512 + n*64 + lane];
      #pragma unroll
      for (int p2 = 0; p2 < 2; ++p2) {
        short8 af = *(const short8*)&X[p2*256 + xrow0][ks*32 + lg*8];
        #pragma unroll
        for (int n = 0; n < 8; ++n)
          acc[p2][n] = __builtin_amdgcn_mfma_f32_16x16x32_bf16(bf[n], af, acc[p2][n], 0, 0, 0);
      }
    }
    // acc[p2][n][q] = H[p2*256 + xrow0][n*16 + cbase + q]
    if (s < 2) {
      const float* bias = (s == 0) ? b2 : pb1;
      #pragma unroll
      for (int p2 = 0; p2 < 2; ++p2)
        #pragma unroll
        for (int n = 0; n < 8; ++n) {
          float4 bq = *(const float4*)(bias + n*16 + cbase);
          float v0 = acc[p2][n][0] + bq.x, v1 = acc[p2][n][1] + bq.y;
          float v2 = acc[p2][n][2] + bq.z, v3 = acc[p2][n][3] + bq.w;
          if (s == 1) {
            v0 = fmaxf(v0, 0.f); v1 = fmaxf(v1, 0.f);
            v2 = fmaxf(v2, 0.f); v3 = fmaxf(v3, 0.f);
          }
          uint2 pk;
          pk.x = (unsigned)f2bf(v0) | ((unsigned)f2bf(v1) << 16);
          pk.y = (unsigned)f2bf(v2) | ((unsigned)f2bf(v3) << 16);
          *(uint2*)&X[p2*256 + xrow0][n*16 + cbase] = pk;
        }
      // same-wave LDS RAW: in-order ds pipeline; no barrier needed
    } else {
      // pass 1: bias add + per-row stats (row = p2*256+xrow0, lane-local)
      float sr[2] = {0,0}, qr[2] = {0,0};
      #pragma unroll
      for (int p2 = 0; p2 < 2; ++p2)
        #pragma unroll
        for (int n = 0; n < 8; ++n) {
          float4 bq = *(const float4*)(pb2 + n*16 + cbase);
          #pragma unroll
          for (int q = 0; q < 4; ++q) {
            float v = acc[p2][n][q] + ((const float*)&bq)[q];
            acc[p2][n][q] = v;
            sr[p2] += v; qr[p2] += v*v;
          }
        }
      #pragma unroll
      for (int p2 = 0; p2 < 2; ++p2) {        // reduce across lg (cols)
        sr[p2] += __shfl_xor(sr[p2], 16, 64);
        sr[p2] += __shfl_xor(sr[p2], 32, 64);
        qr[p2] += __shfl_xor(qr[p2], 16, 64);
        qr[p2] += __shfl_xor(qr[p2], 32, 64);
      }
      float mean[2], rs[2];
      #pragma unroll
      for (int p2 = 0; p2 < 2; ++p2) {
        mean[p2] = sr[p2]*(1.f/128.f);
        float var = qr[p2]*(1.f/128.f) - mean[p2]*mean[p2];
        rs[p2] = rsqrtf(var + 1e-5f);
      }
      // pass 2: per n — normalize, write packed, column partial sums
      #pragma unroll
      for (int n = 0; n < 8; ++n) {
        float4 gq = *(const float4*)(ng  + n*16 + cbase);
        float4 bq = *(const float4*)(nbv + n*16 + cbase);
        float pcq[4] = {0,0,0,0};
        #pragma unroll
        for (int p2 = 0; p2 < 2; ++p2) {
          float xo[4];
          #pragma unroll
          for (int q = 0; q < 4; ++q) {
            xo[q] = (acc[p2][n][q] - mean[p2])*rs[p2]*((const float*)&gq)[q]
                    + ((const float*)&bq)[q];
            pcq[q] += xo[q];
          }
          uint2 pk;
          pk.x = (unsigned)f2bf(xo[0]*PRESCL) | ((unsigned)f2bf(xo[1]*PRESCL) << 16);
          pk.y = (unsigned)f2bf(xo[2]*PRESCL) | ((unsigned)f2bf(xo[3]*PRESCL) << 16);
          *(uint2*)&X[p2*256 + xrow0][n*16 + cbase] = pk;
        }
        #pragma unroll
        for (int msk = 1; msk < 16; msk <<= 1)   // reduce across l15 (rows)
          #pragma unroll
          for (int q = 0; q < 4; ++q) pcq[q] += __shfl_xor(pcq[q], msk, 64);
        if (l15 == 0)
          *(float4*)&gpart[wave][n*16 + cbase] = make_float4(pcq[0],pcq[1],pcq[2],pcq[3]);
      }
    }
  }
  __syncthreads();   // X fully written (pre-scaled), gpart ready

  // ---------------- exit MLP: wave 0 solo, barrier-free ----------------
  if (wave == 0) {
    const int c0 = lane, c1 = lane + 64;
    float m0 = 0.f, m1 = 0.f;
    #pragma unroll
    for (int w = 0; w < 16; ++w) { m0 += gpart[w][c0]; m1 += gpart[w][c1]; }
    mrow[c0] = m0 * (1.f/512.f);
    mrow[c1] = m1 * (1.f/512.f);
    float u0 = eb1[c0], u1 = eb1[c1];
    #pragma unroll 8
    for (int k = 0; k < DIM; ++k) {
      const float mk = mrow[k];
      u0 = fmaf(mk, eW1[k*DIM + c0], u0);
      u1 = fmaf(mk, eW1[k*DIM + c1], u1);
    }
    float s2 = u0 + u1, q2 = u0*u0 + u1*u1;
    #pragma unroll
    for (int msk = 1; msk < 64; msk <<= 1) {
      s2 += __shfl_xor(s2, msk, 64); q2 += __shfl_xor(q2, msk, 64);
    }
    const float mean = s2*(1.f/128.f);
    const float var  = q2*(1.f/128.f) - mean*mean;
    const float rs   = rsqrtf(var + 1e-5f);
    float a0 = fmaxf((u0 - mean)*rs*eg[c0] + ebe[c0], 0.f);
    float a1 = fmaxf((u1 - mean)*rs*eg[c1] + ebe[c1], 0.f);
    float p = a0*eW2[c0] + a1*eW2[c1];
    #pragma unroll
    for (int msk = 1; msk < 64; msk <<= 1) p += __shfl_xor(p, msk, 64);
    if (lane == 0) {
      float e = p + eb2[0];
      out[bb*3 + 0] = 0.f;
      out[bb*3 + 1] = 1.f - e;
      out[bb*3 + 2] = e;
    }
  }
  if (wave == 1) {
    if (lane < 8)   out[768 + bb*8 + lane] = 0.f;   // edge_class
    if (lane == 8)  out[2816 + bb] = 0.f;           // node_class
  }

  // -------- scores: task = (tile, rg-pair); B-frags read once per pair ----
  // acc[r][n][q] = S[gi = ti*128+rg*16+lg*4+q][gj = tj*128+n*16+l15]
  float* ea = out + 3072 + (size_t)bb*EPB;
  for (;;) {
    int task = 0;
    if (lane == 0) task = atomicAdd(&tq, 1);
    task = __shfl(task, 0, 64);
    if (task >= 40) break;
    const int p = task >> 2, rgp = task & 3;
    const int ti = (int)((0x3221110000ULL >> (p*4)) & 0xF);
    const int tj = (int)((0x3323213210ULL >> (p*4)) & 0xF);
    const bool diag = (ti == tj);
    const int rg0 = rgp*2, rg1 = rgp*2 + 1;
    const int nlo0 = diag ? rg0 : 0;

    f32x4 acc[2][8];
    #pragma unroll
    for (int r = 0; r < 2; ++r)
      #pragma unroll
      for (int n = 0; n < 8; ++n) acc[r][n] = (f32x4){0,0,0,0};
    #pragma unroll
    for (int ks = 0; ks < 4; ++ks) {
      const int k0 = ks*32 + lg*8;
      short8 a0 = *(const short8*)&X[ti*128 + rg0*16 + l15][k0];
      short8 a1 = *(const short8*)&X[ti*128 + rg1*16 + l15][k0];
      #pragma unroll
      for (int n = 0; n < 8; ++n) {
        if (n >= nlo0) {
          short8 bfrag = *(const short8*)&X[tj*128 + n*16 + l15][k0];
          acc[0][n] = __builtin_amdgcn_mfma_f32_16x16x32_bf16(a0, bfrag, acc[0][n], 0, 0, 0);
          if (!diag || n >= rg1)
            acc[1][n] = __builtin_amdgcn_mfma_f32_16x16x32_bf16(a1, bfrag, acc[1][n], 0, 0, 0);
        }
      }
    }
    #pragma unroll
    for (int r = 0; r < 2; ++r) {
      const int rg  = rgp*2 + r;
      const int nlo = diag ? rg : 0;
      const int gib = ti*128 + rg*16 + lg*4;
      int rb[4];
      #pragma unroll
      for (int q = 0; q < 4; ++q) {
        const int gi = gib + q;
        rb[q] = gi*511 - ((gi*(gi-1)) >> 1) - gi - 1;
      }
      #pragma unroll
      for (int n = 0; n < 8; ++n) {
        if (n < nlo) continue;
        const int gj = tj*128 + n*16 + l15;
        if (!diag || n > rg) {
          #pragma unroll
          for (int q = 0; q < 4; ++q) ea[rb[q] + gj] = acc[r][n][q];
        } else {          // n == rg on a diagonal tile: per-lane boundary
          #pragma unroll
          for (int q = 0; q < 4; ++q)
            if (gj > gib + q) ea[rb[q] + gj] = acc[r][n][q];
        }
      }
    }
  }
}

extern "C" void kernel_launch(void* const* d_in, const int* in_sizes, int n_in,
                              void* d_out, int out_size, void* d_ws, size_t ws_size,
                              hipStream_t stream) {
  const int*   nf   = (const int*)d_in[0];
  const int*   ei   = (const int*)d_in[1];
  const float* emb  = (const float*)d_in[3];
  const float* gW1  = (const float*)d_in[4];
  const float* gb1  = (const float*)d_in[5];
  const float* gg1  = (const float*)d_in[6];
  const float* gbe1 = (const float*)d_in[7];
  const float* gW2  = (const float*)d_in[8];
  const float* gb2  = (const float*)d_in[9];
  const float* pW1  = (const float*)d_in[10];
  const float* pb1  = (const float*)d_in[11];
  const float* pW2  = (const float*)d_in[12];
  const float* pb2  = (const float*)d_in[13];
  const float* ng   = (const float*)d_in[14];
  const float* nb   = (const float*)d_in[15];
  const float* eW1  = (const float*)d_in[16];
  const float* eb1  = (const float*)d_in[17];
  const float* eg   = (const float*)d_in[18];
  const float* ebe  = (const float*)d_in[19];
  const float* eW2  = (const float*)d_in[20];
  const float* eb2  = (const float*)d_in[21];
  float* out = (float*)d_out;

  char* ws = (char*)d_ws;
  unsigned short* embW1 = (unsigned short*)ws;                 // 131072 B used
  unsigned short* wswz  = (unsigned short*)(ws + 262144);      // 98304 B
  int*            cnt   = (int*)(ws + 360448);                 // 524288 B
  unsigned short* slots = (unsigned short*)(ws + 884736);      // 8388608 B (CAP=32)
  if (ws_size < 9273344) return;

  k_prep  <<<960,  256, 0, stream>>>(emb, gW1, embW1, gW2, pW1, pW2, wswz, cnt);
  k_edges <<<2048, 256, 0, stream>>>(ei, nf, cnt, slots);
  k_mega  <<<256, 1024, 0, stream>>>(embW1, nf, cnt, slots, gb1, gg1, gbe1,
                                     wswz, gb2, pb1, pb2, ng, nb,
                                     eW1, eb1, eg, ebe, eW2, eb2, out);
}